// Round 10
// baseline (1002.809 us; speedup 1.0000x reference)
//
#include <hip/hip_runtime.h>
#include <hip/hip_bf16.h>

// R10: s-row decomposition. 64 blocks = 8 batches x 8 chunks of 16 s-rows.
// Each block computes ALL 512 z-cols for its rows (full W_cell slice in
// VGPRs: 8 waves x 192 regs), so the per-step exchange is just the 2
// boundary h-rows (1 cache line per side, sync degree 2) via R7's tagged
// self-validating protocol. In-chain local via 17-row D-phase.

#define NB 8
#define NT 128
#define NS 128
#define NSTEP 127
#define TPRED 4
#define TOUT 123

typedef __attribute__((ext_vector_type(4))) float f32x4;
typedef __attribute__((ext_vector_type(8))) short s16x8;
typedef __attribute__((ext_vector_type(4))) unsigned int u32x4;

// workspace layout (bytes)
#define WS_WTC 0                        // bf16 [512][384]: col''=q*64+g*16+h, K=[h_before,h,h_after]
#define WS_WT1 (512*384*2)              // bf16 [128][128]: [out_col][k]
#define WS_PUB (WS_WT1 + 128*128*2)     // u32 [2 par][8 b][8 c][2 side][128 col]
#define WS_PUB_BYTES (2*8*8*2*128*4)

// LDS-only barrier (no vmcnt drain; publishes float)
#define BARRIER() do { \
    __builtin_amdgcn_sched_barrier(0); \
    asm volatile("s_waitcnt lgkmcnt(0)" ::: "memory"); \
    __builtin_amdgcn_s_barrier(); \
    __builtin_amdgcn_sched_barrier(0); \
} while (0)

__device__ __forceinline__ unsigned swz(unsigned off) {
    return off ^ (((off >> 8) & 7u) << 4);
}

__global__ void init_weights(const float* __restrict__ Wc, const float* __restrict__ W1,
                             __hip_bfloat16* __restrict__ WTc, __hip_bfloat16* __restrict__ WT1)
{
    int i = blockIdx.x * blockDim.x + threadIdx.x;
    if (i < 512*384) {
        int cpp = i / 384, k = i % 384;
        int q = cpp >> 6, rem = cpp & 63, g = rem >> 4, h = rem & 15;
        int oc = g*128 + 16*q + h;   // original W_cell column
        int row = (k < 128) ? (261 + k) : ((k < 256) ? (5 + (k - 128)) : (133 + (k - 256)));
        WTc[cpp*384 + k] = __float2bfloat16(Wc[row*512 + oc]);
    } else {
        int qq = i - 512*384;
        if (qq < 128*128) {
            int nn = qq >> 7, k = qq & 127;
            WT1[nn*128 + k] = __float2bfloat16(W1[k*128 + nn]);
        }
    }
}

__global__ __launch_bounds__(512, 1) void lstm_persist(
    const float* __restrict__ input, const float* __restrict__ Wc,
    const float* __restrict__ bc, const float* __restrict__ b1v,
    const float* __restrict__ W2, const float* __restrict__ b2,
    float* __restrict__ outp,
    const __hip_bfloat16* __restrict__ WTc, const __hip_bfloat16* __restrict__ WT1,
    unsigned* pub)
{
    __shared__ __align__(16) __hip_bfloat16 hl[2*18*128];    // dbuf: rows 0=s0-1, 1..16 own, 17=s0+16 (swz)
    __shared__ __align__(16) __hip_bfloat16 relu_l[18*128];  // swz, rows 0..16 (out rows 16c-1..16c+15)
    __shared__ float xl[3][80];      // x(t) rows 16c..16c+15, mod-3
    __shared__ float outl[17*3];     // wave-0 private
    __shared__ float w2l[3*128];
    __shared__ float b2l[3];

    const int tid  = threadIdx.x;
    const int blk  = blockIdx.x;
    const int b    = blk & 7;        // batch (R3 mapping: best locality)
    const int c    = blk >> 3;       // s-chunk: rows [16c, 16c+16)
    const int lane = tid & 63;
    const int w    = tid >> 6;       // wave 0..7 = hid group (z-cols for hid 16w..16w+16, 4 gates)
    const int arow = lane & 15;
    const int kgrp = lane >> 4;
    const int hidw = 16*w + arow;    // hid col this lane owns in gate phase

    for (int i = tid; i < 2*18*128; i += 512) ((unsigned short*)hl)[i] = 0;
    if (tid < 384) w2l[tid] = W2[(tid & 127)*3 + (tid >> 7)];
    if (tid >= 384 && tid < 387) b2l[tid - 384] = b2[tid - 384];

    // per-lane constants (x-part weights + biases for hid col hidw, all 4 gates)
    float wxr[4][5], bcr[4];
    #pragma unroll
    for (int g = 0; g < 4; ++g) {
        const int cg = g*128 + hidw;
        bcr[g] = bc[cg];
        #pragma unroll
        for (int f = 0; f < 5; ++f) wxr[g][f] = Wc[f*512 + cg];
    }
    const float b1r = b1v[hidw];

    // full z-weight slice for this wave in registers: 4 gates x 12 kt (192 VGPRs)
    s16x8 brg[4][12];
    #pragma unroll
    for (int g = 0; g < 4; ++g)
        #pragma unroll
        for (int kt = 0; kt < 12; ++kt)
            brg[g][kt] = *(const s16x8*)((const char*)WTc +
                ((unsigned)(w*64 + g*16 + arow)*384 + kt*32 + kgrp*8)*2);
    s16x8 w1r[4];
    #pragma unroll
    for (int kt = 0; kt < 4; ++kt)
        w1r[kt] = *(const s16x8*)((const char*)WT1 + ((unsigned)(hidw)*128 + kt*32 + kgrp*8)*2);

    float cst[4] = {0.f, 0.f, 0.f, 0.f};   // c-state: rows 16c+kgrp*4+r, col hidw

    // stage x(0)
    if (tid < 80) xl[0][tid] = input[((unsigned)(b*NT)*NS + 16*c)*5 + tid];

    __syncthreads();

    for (int j = 0; j <= NSTEP; ++j) {
        const int jm3 = j % 3;
        const unsigned hlb  = (unsigned)(j & 1) * 4608u;        // 18*256 B
        const unsigned nhlb = (unsigned)((j + 1) & 1) * 4608u;

        // ---- gather 2 boundary rows of h(j): tagged poll, 1 dwordx4/thread ----
        if (j > 0 && tid < 64) {
            const bool left = (tid < 32);
            if (left ? (c > 0) : (c < 7)) {
                const unsigned jt = (unsigned)j;
                const int nc   = left ? (c - 1) : (c + 1);
                const int side = left ? 1 : 0;      // left nbr's last row / right nbr's first row
                const int col4 = (tid & 31) * 4;
                const unsigned* q = pub + (unsigned)(((j & 1)*8 + b)*8 + nc)*256 + side*128 + col4;
                u32x4 g;
                for (;;) {
                    asm volatile("global_load_dwordx4 %0, %1, off sc0 sc1\n\ts_waitcnt vmcnt(0)"
                                 : "=v"(g) : "v"(q) : "memory");
                    if ((g[0] >> 16) == jt && (g[1] >> 16) == jt &&
                        (g[2] >> 16) == jt && (g[3] >> 16) == jt) break;
                }
                __builtin_amdgcn_sched_barrier(0);
                const unsigned long long pk =
                    (unsigned long long)(g[0] & 0xffffu)        |
                    ((unsigned long long)(g[1] & 0xffffu) << 16) |
                    ((unsigned long long)(g[2] & 0xffffu) << 32) |
                    ((unsigned long long)(g[3] & 0xffffu) << 48);
                const int row = left ? 0 : 17;
                *(unsigned long long*)((char*)hl + hlb + swz((unsigned)(row*256 + col4*2))) = pk;
            }
        }
        // ---- issue x(j+1) loads early (T14: commit to LDS at loop bottom) ----
        float xr = 0.f;
        const bool xact = (j < NSTEP) && (tid < 80);
        if (xact) xr = input[((unsigned)(b*NT + j + 1)*NS + 16*c)*5 + tid];

        BARRIER();  // B1: hl[j&1] complete (rows 0..17), xl[jm3] ready

        // ---- z-GEMM M=16 N=512 K=384 (B fully in regs) + gates -> h(j+1); publish ----
        if (j < NSTEP) {
            f32x4 a0 = {0.f,0.f,0.f,0.f}, a1 = a0, a2 = a0, a3 = a0;
            const unsigned ab = (unsigned)(arow*256 + kgrp*16);
            #pragma unroll
            for (int kt = 0; kt < 4; ++kt) {     // h_before: LDS rows 0..15
                const s16x8 av = *(const s16x8*)((const char*)hl + hlb + swz(ab + kt*64));
                a0 = __builtin_amdgcn_mfma_f32_16x16x32_bf16(av, brg[0][kt], a0, 0, 0, 0);
                a1 = __builtin_amdgcn_mfma_f32_16x16x32_bf16(av, brg[1][kt], a1, 0, 0, 0);
                a2 = __builtin_amdgcn_mfma_f32_16x16x32_bf16(av, brg[2][kt], a2, 0, 0, 0);
                a3 = __builtin_amdgcn_mfma_f32_16x16x32_bf16(av, brg[3][kt], a3, 0, 0, 0);
            }
            #pragma unroll
            for (int kt = 4; kt < 8; ++kt) {     // h: rows 1..16
                const s16x8 av = *(const s16x8*)((const char*)hl + hlb + swz(ab + 256 + (kt-4)*64));
                a0 = __builtin_amdgcn_mfma_f32_16x16x32_bf16(av, brg[0][kt], a0, 0, 0, 0);
                a1 = __builtin_amdgcn_mfma_f32_16x16x32_bf16(av, brg[1][kt], a1, 0, 0, 0);
                a2 = __builtin_amdgcn_mfma_f32_16x16x32_bf16(av, brg[2][kt], a2, 0, 0, 0);
                a3 = __builtin_amdgcn_mfma_f32_16x16x32_bf16(av, brg[3][kt], a3, 0, 0, 0);
            }
            #pragma unroll
            for (int kt = 8; kt < 12; ++kt) {    // h_after: rows 2..17
                const s16x8 av = *(const s16x8*)((const char*)hl + hlb + swz(ab + 512 + (kt-8)*64));
                a0 = __builtin_amdgcn_mfma_f32_16x16x32_bf16(av, brg[0][kt], a0, 0, 0, 0);
                a1 = __builtin_amdgcn_mfma_f32_16x16x32_bf16(av, brg[1][kt], a1, 0, 0, 0);
                a2 = __builtin_amdgcn_mfma_f32_16x16x32_bf16(av, brg[2][kt], a2, 0, 0, 0);
                a3 = __builtin_amdgcn_mfma_f32_16x16x32_bf16(av, brg[3][kt], a3, 0, 0, 0);
            }
            // drain 2-step-old same-address publishes (+x loads, long retired): ~0 cost
            asm volatile("s_waitcnt vmcnt(0)" ::: "memory");
            unsigned short h0b = 0, h3b = 0;
            #pragma unroll
            for (int r = 0; r < 4; ++r) {
                const int lr0 = kgrp*4 + r;      // local row 0..15 (global 16c+lr0)
                const float xv0 = xl[jm3][lr0*5+0], xv1 = xl[jm3][lr0*5+1], xv2 = xl[jm3][lr0*5+2],
                            xv3 = xl[jm3][lr0*5+3], xv4 = xl[jm3][lr0*5+4];
                const float iv = a0[r] + bcr[0] + xv0*wxr[0][0] + xv1*wxr[0][1] + xv2*wxr[0][2] + xv3*wxr[0][3] + xv4*wxr[0][4];
                const float fv = a1[r] + bcr[1] + xv0*wxr[1][0] + xv1*wxr[1][1] + xv2*wxr[1][2] + xv3*wxr[1][3] + xv4*wxr[1][4];
                const float gv = a2[r] + bcr[2] + xv0*wxr[2][0] + xv1*wxr[2][1] + xv2*wxr[2][2] + xv3*wxr[2][3] + xv4*wxr[2][4];
                const float ov = a3[r] + bcr[3] + xv0*wxr[3][0] + xv1*wxr[3][1] + xv2*wxr[3][2] + xv3*wxr[3][3] + xv4*wxr[3][4];
                const float si = __builtin_amdgcn_rcpf(1.f + __expf(-iv));
                const float sf = __builtin_amdgcn_rcpf(1.f + __expf(-fv));
                const float so = __builtin_amdgcn_rcpf(1.f + __expf(-ov));
                const float tg = 1.f - 2.f*__builtin_amdgcn_rcpf(__expf(2.f*gv) + 1.f);
                const float cn = sf*cst[r] + si*tg;
                cst[r] = cn;
                const float tc = 1.f - 2.f*__builtin_amdgcn_rcpf(__expf(2.f*cn) + 1.f);
                const float hn = so*tc;
                __hip_bfloat16 hbv = __float2bfloat16(hn);
                const unsigned short hbits = *(const unsigned short*)&hbv;
                *(unsigned short*)((char*)hl + nhlb + swz((unsigned)((lr0 + 1)*256 + hidw*2))) = hbits;
                if (r == 0) h0b = hbits;
                if (r == 3) h3b = hbits;
            }
            // publish boundary rows (tagged, fire-and-forget)
            unsigned* pbase = pub + (unsigned)((((j+1) & 1)*8 + b)*8 + c)*256;
            const unsigned jt1 = (unsigned)(j + 1) << 16;
            if (c > 0 && kgrp == 0)   // row 16c (lanes' r=0) -> side 0
                asm volatile("global_store_dword %0, %1, off sc0 sc1"
                             :: "v"(pbase + hidw), "v"(jt1 | (unsigned)h0b) : "memory");
            if (c < 7 && kgrp == 3)   // row 16c+15 (lanes' r=3) -> side 1
                asm volatile("global_store_dword %0, %1, off sc0 sc1"
                             :: "v"(pbase + 128 + hidw), "v"(jt1 | (unsigned)h3b) : "memory");
        }

        // ---- D: out(j-1) from h(j), local rows 0..16 (global 16c-1..16c+15) ----
        if (j >= TPRED + 1) {
            const int jm1_3 = (j - 1) % 3;
            f32x4 c0 = {0.f,0.f,0.f,0.f}, c1 = c0;
            const unsigned w1a = (unsigned)(arow*256 + kgrp*16);
            #pragma unroll
            for (int kt = 0; kt < 4; ++kt) {
                const s16x8 av0 = *(const s16x8*)((const char*)hl + hlb + swz(w1a + kt*64));        // rows 0..15
                const s16x8 av1 = *(const s16x8*)((const char*)hl + hlb + swz(w1a + 256 + kt*64));  // rows 1..16
                c0 = __builtin_amdgcn_mfma_f32_16x16x32_bf16(av0, w1r[kt], c0, 0, 0, 0);
                c1 = __builtin_amdgcn_mfma_f32_16x16x32_bf16(av1, w1r[kt], c1, 0, 0, 0);
            }
            #pragma unroll
            for (int r = 0; r < 4; ++r) {
                const int lr = kgrp*4 + r;
                const float v0 = fmaxf(c0[r] + b1r, 0.f);
                *(__hip_bfloat16*)((char*)relu_l + swz((unsigned)(lr*256 + hidw*2))) = __float2bfloat16(v0);
                if (lr == 15) {
                    const float v1 = fmaxf(c1[r] + b1r, 0.f);
                    *(__hip_bfloat16*)((char*)relu_l + swz((unsigned)(16*256 + hidw*2))) = __float2bfloat16(v1);
                }
            }
            BARRIER();  // B3
            if (tid < 51) {
                const int m = tid / 3, p = tid - m*3;
                float s = b2l[p];
                #pragma unroll
                for (int kc = 0; kc < 16; ++kc) {
                    union { s16x8 v; unsigned short u[8]; } uu;
                    uu.v = *(const s16x8*)((const char*)relu_l + swz((unsigned)(m*256 + kc*16)));
                    #pragma unroll
                    for (int e = 0; e < 8; ++e)
                        s += __uint_as_float((unsigned)uu.u[e] << 16) * w2l[p*128 + kc*8 + e];
                }
                outl[m*3 + p] = s;   // out(global 16c-1+m)
            }
            // outl written & read by wave 0 only -> same-wave LDS in-order
            if (tid < 16) {
                const int m = tid, grow = 16*c + m;
                const float no = outl[(m + 1)*3 + 0];
                float In, sp0, sp1;
                if (m == 0 && c == 0) { In = xl[jm3][1]; sp0 = xl[jm3][3]; sp1 = xl[jm3][4]; }
                else { In = outl[m*3 + 0]; sp0 = outl[(m + 1)*3 + 1]; sp1 = outl[(m + 1)*3 + 2]; }
                const float former = xl[jm1_3][m*5 + 2];
                const long base = ((long)(b*TOUT + (j - 1 - TPRED))*NS + grow)*5;
                outp[base + 0] = no;
                outp[base + 1] = In;
                outp[base + 2] = former + In - no;
                outp[base + 3] = sp0;
                outp[base + 4] = sp1;
            }
        }

        // ---- commit x(j+1) to LDS (read next iter after B1) ----
        if (xact) xl[(j + 1) % 3][tid] = xr;
    }
}

extern "C" void kernel_launch(void* const* d_in, const int* in_sizes, int n_in,
                              void* d_out, int out_size, void* d_ws, size_t ws_size,
                              hipStream_t stream) {
    const float* input = (const float*)d_in[0];
    const float* Wc    = (const float*)d_in[1];
    const float* bc    = (const float*)d_in[2];
    const float* W1    = (const float*)d_in[3];
    const float* b1    = (const float*)d_in[4];
    const float* W2    = (const float*)d_in[5];
    const float* b2    = (const float*)d_in[6];
    float* outp = (float*)d_out;
    char* ws = (char*)d_ws;

    __hip_bfloat16* WTc = (__hip_bfloat16*)(ws + WS_WTC);
    __hip_bfloat16* WT1 = (__hip_bfloat16*)(ws + WS_WT1);
    unsigned*       pub = (unsigned*)(ws + WS_PUB);

    hipMemsetAsync(ws + WS_PUB, 0, WS_PUB_BYTES, stream);   // tags=0: never matches j>=1
    init_weights<<<832, 256, 0, stream>>>(Wc, W1, WTc, WT1);
    lstm_persist<<<64, 512, 0, stream>>>(input, Wc, bc, b1, W2, b2, outp, WTc, WT1, pub);
}